// Round 1
// 603.437 us; speedup vs baseline: 1.4534x; 1.4534x over previous
//
#include <hip/hip_runtime.h>
#include <math.h>

// Problem constants
#define N_TOK 1024
#define TOPK  2
#define NEXP  16
#define HID   1024   // H
#define DIM   2048   // D
#define RANK  16
#define NPAIR (N_TOK * TOPK)
#define MOE_SCALE 0.25f
#define MAXTILES 31  // sum_e ceil(cnt_e/128) <= 15 + 16

typedef __attribute__((ext_vector_type(8))) short short8;
typedef __attribute__((ext_vector_type(4))) float floatx4;

static __device__ __forceinline__ unsigned short f2bf(float f) {
    union { float f; unsigned int u; } v; v.f = f;
    unsigned int u = v.u;
    u += 0x7fffu + ((u >> 16) & 1u);   // RNE
    return (unsigned short)(u >> 16);
}

static __device__ __forceinline__ short8 cvt8(float4 a, float4 b) {
    short8 o;
    o[0] = (short)f2bf(a.x); o[1] = (short)f2bf(a.y);
    o[2] = (short)f2bf(a.z); o[3] = (short)f2bf(a.w);
    o[4] = (short)f2bf(b.x); o[5] = (short)f2bf(b.y);
    o[6] = (short)f2bf(b.z); o[7] = (short)f2bf(b.w);
    return o;
}

// Raw barrier: lgkmcnt(0) drains our ds_writes (producer side); the raw
// s_barrier builtin does NOT drain vmcnt, so the depth-2 register prefetch
// (plain global->VGPR loads) stays in flight across iterations.
#define BAR() do { asm volatile("s_waitcnt lgkmcnt(0)" ::: "memory"); \
                   __builtin_amdgcn_s_barrier(); } while (0)

// ---------------------------------------------------------------------------
// Routing: sort pair indices by expert + dense (e,mt) worklist (XCD-friendly).
// ---------------------------------------------------------------------------
__global__ void k_routing(const int* __restrict__ ids,
                          int* __restrict__ offs,      // [NEXP+1]
                          int* __restrict__ sorted,    // [NPAIR]
                          int* __restrict__ tlist,     // [MAXTILES] (e<<8|mt)
                          int* __restrict__ tcount) {
    __shared__ int s_cnt[NEXP];
    __shared__ int s_off[NEXP + 1];
    int tid = threadIdx.x;
    if (tid < NEXP) s_cnt[tid] = 0;
    __syncthreads();
    for (int p = tid; p < NPAIR; p += blockDim.x) atomicAdd(&s_cnt[ids[p]], 1);
    __syncthreads();
    if (tid == 0) {
        int acc = 0;
        for (int e = 0; e < NEXP; ++e) { s_off[e] = acc; acc += s_cnt[e]; }
        s_off[NEXP] = acc;
        int t = 0;
        for (int e = 0; e < NEXP; ++e) {
            int c = s_off[e + 1] - s_off[e];
            for (int m = 0; m * 128 < c; ++m) tlist[t++] = (e << 8) | m;
        }
        *tcount = t;
    }
    __syncthreads();
    if (tid <= NEXP) offs[tid] = s_off[tid];
    if (tid < NEXP) s_cnt[tid] = s_off[tid];
    __syncthreads();
    for (int p = tid; p < NPAIR; p += blockDim.x) {
        int e = ids[p];
        int slot = atomicAdd(&s_cnt[e], 1);
        sorted[slot] = p;
    }
}

// ---------------------------------------------------------------------------
// x (fp32) -> bf16, once. Halves A-staging loads + removes A cvt in k_up.
// ---------------------------------------------------------------------------
__global__ void k_cvt_x(const float* __restrict__ x, unsigned short* __restrict__ xbf) {
    size_t i = (size_t)blockIdx.x * blockDim.x + threadIdx.x;   // 8 elems/thread
    const float4* p = (const float4*)(x + i * 8);
    float4 a = p[0], b = p[1];
    *(short8*)(xbf + i * 8) = cvt8(a, b);
}

// ---------------------------------------------------------------------------
// Shared GEMM building blocks (both k_up and k_down declare identically-named
// locals: sA,sB,sU, aptr,bptr,uptr, row,colh, urow, tid,wv,lm,lq, acc,acct,
// ra0/ra1, rb0/rb1, ru0/ru1). All register arrays are statically indexed.
//
// Per chunk (BK=64):
//   A: 128x64 bf16 loaded directly (16 KB), B: 128x64 fp32 -> cvt bf16,
//   U: 16x64 of lora-A rows (fp32 -> bf16) staged by waves 0-1 only.
// Depth-2 staging: chunk c lives in reg slot (c&1); LDS double-buffered.
// ---------------------------------------------------------------------------
#define G_ISSUE(c, RA, RB, RU) do {                                          \
    const unsigned short* _a = aptr + (size_t)(c) * 64;                      \
    const float* _b = bptr + (size_t)(c) * 64;                               \
    _Pragma("unroll") for (int j = 0; j < 4; ++j)                            \
        RA[j] = *(const short8*)(_a + 8 * j);                                \
    _Pragma("unroll") for (int j = 0; j < 8; ++j)                            \
        RB[j] = *(const float4*)(_b + 4 * j);                                \
    if (tid < 128) {                                                         \
        const float* _u = uptr + (size_t)(c) * 64;                           \
        RU[0] = *(const float4*)_u;                                          \
        RU[1] = *(const float4*)(_u + 4);                                    \
    }                                                                        \
} while (0)

#define G_WRITE(RA, RB, RU, BUF) do {                                        \
    _Pragma("unroll") for (int cc = 0; cc < 4; ++cc) {                       \
        int cl = (tid & 1) * 4 + cc;                                         \
        *(short8*)(&sA[BUF][row * 64 + ((cl ^ (row & 7)) * 8)]) = RA[cc];    \
        short8 vb = cvt8(RB[2 * cc], RB[2 * cc + 1]);                        \
        *(short8*)(&sB[BUF][row * 64 + ((cl ^ (row & 7)) * 8)]) = vb;        \
    }                                                                        \
    if (tid < 128) {                                                         \
        short8 vu = cvt8(RU[0], RU[1]);                                      \
        int cl = tid & 7;                                                    \
        *(short8*)(&sU[BUF][urow * 64 + ((cl ^ (urow & 7)) * 8)]) = vu;      \
    }                                                                        \
} while (0)

#define G_MSTEP(BUF) do {                                                    \
    _Pragma("unroll") for (int kk = 0; kk < 2; ++kk) {                       \
        int r0 = wv * 32 + lm, r1 = wv * 32 + 16 + lm;                       \
        short8 af0 = *(const short8*)(&sA[BUF][r0 * 64 + (((kk * 4 + lq) ^ (r0 & 7)) * 8)]); \
        short8 af1 = *(const short8*)(&sA[BUF][r1 * 64 + (((kk * 4 + lq) ^ (r1 & 7)) * 8)]); \
        short8 uf  = *(const short8*)(&sU[BUF][lm * 64 + (((kk * 4 + lq) ^ (lm & 7)) * 8)]); \
        acct[0] = __builtin_amdgcn_mfma_f32_16x16x32_bf16(af0, uf, acct[0], 0, 0, 0); \
        acct[1] = __builtin_amdgcn_mfma_f32_16x16x32_bf16(af1, uf, acct[1], 0, 0, 0); \
        _Pragma("unroll") for (int n2 = 0; n2 < 8; ++n2) {                   \
            int rr = n2 * 16 + lm;                                           \
            short8 bf = *(const short8*)(&sB[BUF][rr * 64 + (((kk * 4 + lq) ^ (rr & 7)) * 8)]); \
            acc[0][n2] = __builtin_amdgcn_mfma_f32_16x16x32_bf16(af0, bf, acc[0][n2], 0, 0, 0); \
            acc[1][n2] = __builtin_amdgcn_mfma_f32_16x16x32_bf16(af1, bf, acc[1][n2], 0, 0, 0); \
        }                                                                    \
    }                                                                        \
} while (0)

// Depth-2 pipeline: chunk c issued ~2.3 iterations before its LDS write
// waits on it; steady state keeps 2 chunks of loads in flight per wave.
#define G_PIPE(NC)                                                           \
    G_ISSUE(0, ra0, rb0, ru0);                                               \
    G_ISSUE(1, ra1, rb1, ru1);                                               \
    G_WRITE(ra0, rb0, ru0, 0);                                               \
    G_ISSUE(2, ra0, rb0, ru0);                                               \
    BAR();                                                                   \
    _Pragma("unroll 1")                                                      \
    for (int kc = 0; kc < (NC); kc += 2) {                                   \
        G_MSTEP(0);                                                          \
        G_WRITE(ra1, rb1, ru1, 1);                                           \
        if (kc + 3 < (NC)) G_ISSUE(kc + 3, ra1, rb1, ru1);                   \
        BAR();                                                               \
        G_MSTEP(1);                                                          \
        if (kc + 2 < (NC)) G_WRITE(ra0, rb0, ru0, 0);                        \
        if (kc + 4 < (NC)) G_ISSUE(kc + 4, ra0, rb0, ru0);                   \
        BAR();                                                               \
    }

// ---------------------------------------------------------------------------
// Up-GEMM: 128 tokens x 128 cols (64 gate + 64 mul), BK=64, NC=32.
// Fused: t = SCALE * x . up_a^T via one extra MFMA column per kk ("acct"),
// spilled to LDS t_s for the LoRA epilogue (k_tup eliminated).
// ---------------------------------------------------------------------------
__global__ __launch_bounds__(256, 2) void k_up(
        const unsigned short* __restrict__ xbf, const float* __restrict__ w_up,
        const float* __restrict__ up_a, const float* __restrict__ up_b,
        const int* __restrict__ offs, const int* __restrict__ sorted,
        const int* __restrict__ tlist, const int* __restrict__ tcount,
        unsigned short* __restrict__ act) {
    int wt = blockIdx.x;
    if (wt >= *tcount) return;
    int code = tlist[wt];
    int e = code >> 8, mt = code & 255;
    int nt = blockIdx.y;
    int off = offs[e], cnt = offs[e + 1] - off;

    __shared__ __align__(16) unsigned short sA[2][128 * 64];   // 32 KB
    __shared__ __align__(16) unsigned short sB[2][128 * 64];   // 32 KB
    __shared__ __align__(16) unsigned short sU[2][16 * 64];    //  4 KB

    int tid = threadIdx.x, lane = tid & 63, wv = tid >> 6;
    int lm = lane & 15, lq = lane >> 4;

    int row  = tid >> 1;          // 0..127
    int colh = (tid & 1) * 32;    // element col offset within 64-wide chunk

    int g = mt * 128 + row; if (g >= cnt) g = cnt - 1;   // clamp (dup rows ok)
    int p = sorted[off + g];
    const unsigned short* aptr = xbf + (size_t)(p >> 1) * DIM + colh;

    int wrow = (row < 64) ? (nt * 64 + row) : (HID + nt * 64 + (row - 64));
    const float* bptr = w_up + ((size_t)e * 2 * HID + wrow) * DIM + colh;

    int urow = (tid >> 3) & 15, ucol = (tid & 7) * 8;     // waves 0-1 stage U
    const float* uptr = up_a + ((size_t)e * RANK + urow) * DIM + ucol;

    floatx4 zero = {0.f, 0.f, 0.f, 0.f};
    floatx4 acc[2][8], acct[2];
#pragma unroll
    for (int i = 0; i < 2; ++i) {
        acct[i] = zero;
#pragma unroll
        for (int j = 0; j < 8; ++j) acc[i][j] = zero;
    }

    short8 ra0[4], ra1[4];
    float4 rb0[8], rb1[8];
    float4 ru0[2], ru1[2];

    G_PIPE(32);

    // spill t (lora-A dots) to LDS; sA is dead after the final barrier
    float* t_s = (float*)&sA[0][0];   // [128][16] fp32 = 8 KB
#pragma unroll
    for (int i = 0; i < 2; ++i)
#pragma unroll
        for (int j = 0; j < 4; ++j)
            t_s[(wv * 32 + i * 16 + lq * 4 + j) * 16 + lm] = MOE_SCALE * acct[i][j];
    BAR();

    // epilogue: LoRA rank-16 + erf-gelu * mul -> act[slot][h] (bf16)
    const float* upb = up_b + (size_t)e * 2 * HID * RANK;
#pragma unroll
    for (int n2 = 0; n2 < 4; ++n2) {
        int h = nt * 64 + n2 * 16 + lm;
        const float* b1 = upb + (size_t)h * RANK;
        const float* b2 = upb + (size_t)(h + HID) * RANK;
        float r1[RANK], r2[RANK];
#pragma unroll
        for (int i = 0; i < RANK; ++i) { r1[i] = b1[i]; r2[i] = b2[i]; }
#pragma unroll
        for (int i = 0; i < 2; ++i) {
#pragma unroll
            for (int r = 0; r < 4; ++r) {
                int rl = wv * 32 + i * 16 + lq * 4 + r;
                int gg = mt * 128 + rl;
                if (gg < cnt) {
                    int slot = off + gg;
                    const float* tv = t_s + rl * 16;
                    float s1 = acc[i][n2][r], s2 = acc[i][n2 + 4][r];
#pragma unroll
                    for (int j = 0; j < RANK; ++j) { s1 += tv[j] * r1[j]; s2 += tv[j] * r2[j]; }
                    float gl = 0.5f * s1 * (1.f + erff(s1 * 0.70710678118654752f));
                    act[(size_t)slot * HID + h] = f2bf(gl * s2);
                }
            }
        }
    }
}

// ---------------------------------------------------------------------------
// Down-GEMM: 128 tokens x 128 d-rows, BK=64, NC=16. A = act (bf16, direct).
// Fused: t2 = SCALE * act . down_a^T (k_t2 eliminated).
// Epilogue: LoRA + topk-weight + atomic scatter-add.
// ---------------------------------------------------------------------------
__global__ __launch_bounds__(256, 2) void k_down(
        const unsigned short* __restrict__ actg, const float* __restrict__ w_down,
        const float* __restrict__ tw, const float* __restrict__ down_a,
        const float* __restrict__ down_b,
        const int* __restrict__ offs, const int* __restrict__ sorted,
        const int* __restrict__ tlist, const int* __restrict__ tcount,
        float* __restrict__ out) {
    int wt = blockIdx.x;
    if (wt >= *tcount) return;
    int code = tlist[wt];
    int e = code >> 8, mt = code & 255;
    int nt = blockIdx.y;
    int off = offs[e], cnt = offs[e + 1] - off;

    __shared__ __align__(16) unsigned short sA[2][128 * 64];
    __shared__ __align__(16) unsigned short sB[2][128 * 64];
    __shared__ __align__(16) unsigned short sU[2][16 * 64];

    int tid = threadIdx.x, lane = tid & 63, wv = tid >> 6;
    int lm = lane & 15, lq = lane >> 4;

    int row  = tid >> 1;
    int colh = (tid & 1) * 32;

    int g = mt * 128 + row; if (g >= cnt) g = cnt - 1;
    const unsigned short* aptr = actg + (size_t)(off + g) * HID + colh;

    int d = nt * 128 + row;
    const float* bptr = w_down + ((size_t)e * DIM + d) * HID + colh;

    int urow = (tid >> 3) & 15, ucol = (tid & 7) * 8;
    const float* uptr = down_a + ((size_t)e * RANK + urow) * HID + ucol;

    floatx4 zero = {0.f, 0.f, 0.f, 0.f};
    floatx4 acc[2][8], acct[2];
#pragma unroll
    for (int i = 0; i < 2; ++i) {
        acct[i] = zero;
#pragma unroll
        for (int j = 0; j < 8; ++j) acc[i][j] = zero;
    }

    short8 ra0[4], ra1[4];
    float4 rb0[8], rb1[8];
    float4 ru0[2], ru1[2];

    G_PIPE(16);

    float* t_s = (float*)&sA[0][0];
#pragma unroll
    for (int i = 0; i < 2; ++i)
#pragma unroll
        for (int j = 0; j < 4; ++j)
            t_s[(wv * 32 + i * 16 + lq * 4 + j) * 16 + lm] = MOE_SCALE * acct[i][j];
    BAR();

#pragma unroll
    for (int n2 = 0; n2 < 8; ++n2) {
        int dd = nt * 128 + n2 * 16 + lm;
        const float* rb = down_b + ((size_t)e * DIM + dd) * RANK;
        float rbv[RANK];
#pragma unroll
        for (int i2 = 0; i2 < RANK; ++i2) rbv[i2] = rb[i2];
#pragma unroll
        for (int i = 0; i < 2; ++i) {
#pragma unroll
            for (int r = 0; r < 4; ++r) {
                int rl = wv * 32 + i * 16 + lq * 4 + r;
                int gg = mt * 128 + rl;
                if (gg < cnt) {
                    int slot = off + gg;
                    int pp = sorted[slot];
                    const float* tv = t_s + rl * 16;
                    float val = acc[i][n2][r];
#pragma unroll
                    for (int j = 0; j < RANK; ++j) val += tv[j] * rbv[j];
                    atomicAdd(&out[(size_t)(pp >> 1) * DIM + dd], val * tw[pp]);
                }
            }
        }
    }
}

// ---------------------------------------------------------------------------
extern "C" void kernel_launch(void* const* d_in, const int* in_sizes, int n_in,
                              void* d_out, int out_size, void* d_ws, size_t ws_size,
                              hipStream_t stream) {
    const float* x      = (const float*)d_in[0];
    const float* tw     = (const float*)d_in[1];
    const int*   ids    = (const int*)d_in[2];
    const float* w_up   = (const float*)d_in[3];
    const float* w_down = (const float*)d_in[4];
    const float* up_a   = (const float*)d_in[5];
    const float* up_b   = (const float*)d_in[6];
    const float* down_a = (const float*)d_in[7];
    const float* down_b = (const float*)d_in[8];
    float* out = (float*)d_out;

    char* ws = (char*)d_ws;
    int* offs   = (int*)ws;                                  // 68 B
    int* tlist  = (int*)(ws + 1024);                         // 124 B
    int* tcount = (int*)(ws + 2048);                         // 4 B
    int* sorted = (int*)(ws + 4096);                         // 8 KB
    unsigned short* act = (unsigned short*)(ws + 65536);     // 4 MB (NPAIR*HID bf16)
    unsigned short* xbf = (unsigned short*)(ws + 65536 + (size_t)NPAIR * HID * 2); // 4 MB

    hipMemsetAsync(d_out, 0, (size_t)out_size * sizeof(float), stream);

    k_routing<<<1, 256, 0, stream>>>(ids, offs, sorted, tlist, tcount);
    k_cvt_x<<<(N_TOK * DIM / 8 / 256), 256, 0, stream>>>(x, xbf);

    dim3 grid(MAXTILES, 16);
    k_up<<<grid, 256, 0, stream>>>(xbf, w_up, up_a, up_b, offs, sorted, tlist, tcount, act);
    k_down<<<grid, 256, 0, stream>>>(act, w_down, tw, down_a, down_b, offs, sorted, tlist, tcount, out);
}